// Round 7
// baseline (116.944 us; speedup 1.0000x reference)
//
#include <hip/hip_runtime.h>
#include <math.h>

#define BSZ 15
#define NA  225
typedef unsigned long long u64;

// weight chain (cndmask, no indexed array)
__device__ __forceinline__ float wtab(int n) {  // n>=1; n>=5 -> 1e5
    return n == 1 ? 5.f : n == 2 ? 50.f : n == 3 ? 500.f : n == 4 ? 5000.f : 100000.f;
}
__device__ __forceinline__ float wredSum(float v) {
    #pragma unroll
    for (int off = 32; off; off >>= 1) v += __shfl_xor(v, off, 64);
    return v;
}
__device__ __forceinline__ float wredMax(float v) {
    #pragma unroll
    for (int off = 32; off; off >>= 1) v = fmaxf(v, __shfl_xor(v, off, 64));
    return v;
}

struct Masks { u64 P0, P1, P2, P3, O0, O1, O2, O3; };

template<int DIV, int CEXTRA, bool HAS64>
__device__ __forceinline__ void extractWin(int u, const Masks& M, u64 wmask,
                                           int& pc, int& oc, int& idx)
{
    const int r = u / DIV;              // compile-time divisor -> magic mul
    const int c = u % DIV + CEXTRA;
    idx = r * BSZ + c;
    const int q = idx >> 6, sh = idx & 63;
    const u64 Plo = (q & 2) ? ((q & 1) ? M.P3 : M.P2) : ((q & 1) ? M.P1 : M.P0);
    const u64 Phi = (q & 2) ? ((q & 1) ? 0ULL : M.P3) : ((q & 1) ? M.P2 : M.P1);
    const u64 Olo = (q & 2) ? ((q & 1) ? M.O3 : M.O2) : ((q & 1) ? M.O1 : M.O0);
    const u64 Ohi = (q & 2) ? ((q & 1) ? 0ULL : M.O3) : ((q & 1) ? M.O2 : M.O1);
    const u64 xP = (Plo >> sh) | ((Phi << (63 - sh)) << 1);  // sh==0 safe
    const u64 xO = (Olo >> sh) | ((Ohi << (63 - sh)) << 1);
    pc = __popcll(xP & wmask);
    oc = __popcll(xO & wmask);
    if (HAS64) {  // step-16 window spans 65 bits: cell4 = bit sh of hi chunk
        pc += (int)((Phi >> sh) & 1ULL);
        oc += (int)((Ohi >> sh) & 1ULL);
    }
}

template<int STEP>
__device__ __forceinline__ void scoreWin(bool act, int pc, int oc, int idx,
                                         float* __restrict__ bD,
                                         float* __restrict__ bW,
                                         float& baseLocal)
{
    if (!act) return;
    const bool z_oc = (oc == 0), z_pc = (pc == 0);
    const float s0 = z_oc ? (z_pc ? 0.f : wtab(pc)) : (z_pc ? -wtab(oc) : 0.f);
    const float d  = (z_oc ? wtab(pc + 1) : 0.f) - s0;   // wscore(pc+1,oc)-s0
    baseLocal += s0;
    if (d != 0.f) {  // ~26% of windows
        #pragma unroll
        for (int k = 0; k < 5; ++k) atomicAdd(&bD[idx + k * STEP], d);
    }
    if (pc == 4 && z_oc) {
        #pragma unroll
        for (int k = 0; k < 5; ++k) bW[idx + k * STEP] = 1.f;  // benign race
    }
}

// ---- k1: window pass -> prelogit[225] + base, per board ----
__global__ __launch_bounds__(256, 4) void win_kernel(
    const int* __restrict__ boards, const int* __restrict__ cur,
    float* __restrict__ ws, int B)
{
    const int wid  = threadIdx.x >> 6;
    const int lane = threadIdx.x & 63;
    const int b    = blockIdx.x * 4 + wid;

    __shared__ float sDelta[4][NA];
    __shared__ float sWin[4][NA];

    if (b >= B) return;  // whole wave exits; no barriers

    float* __restrict__ bD = sDelta[wid];
    float* __restrict__ bW = sWin[wid];

    const int player = cur[b];
    const int opp    = 3 - player;
    const int* __restrict__ gb = boards + (size_t)b * NA;

    const int v0 = gb[lane];
    const int v1 = gb[lane + 64];
    const int v2 = gb[lane + 128];
    const int v3 = (lane + 192 < NA) ? gb[lane + 192] : -1;

    Masks M;
    M.P0 = __ballot(v0 == player); M.O0 = __ballot(v0 == opp);
    M.P1 = __ballot(v1 == player); M.O1 = __ballot(v1 == opp);
    M.P2 = __ballot(v2 == player); M.O2 = __ballot(v2 == opp);
    M.P3 = __ballot(v3 == player); M.O3 = __ballot(v3 == opp);

    bD[lane] = 0.f;       bW[lane] = 0.f;
    bD[lane + 64] = 0.f;  bW[lane + 64] = 0.f;
    bD[lane + 128] = 0.f; bW[lane + 128] = 0.f;
    if (lane + 192 < NA) { bD[lane + 192] = 0.f; bW[lane + 192] = 0.f; }
    __threadfence_block();

    const u64 MH = 0x1FULL;
    const u64 MV = 0x1000200040008001ULL;   // bits 0,15,30,45,60
    const u64 MD = 0x0001000100010001ULL;   // bits 0,16,32,48 (+bit64)
    const u64 MA = 0x0100040010004001ULL;   // bits 0,14,28,42,56

    int pcS[10], ocS[10], ixS[10];
    const bool a2 = lane < 37, a7 = lane < 57;
    extractWin<11, 0, false>(lane,                 M, MH, pcS[0], ocS[0], ixS[0]);
    extractWin<11, 0, false>(lane + 64,            M, MH, pcS[1], ocS[1], ixS[1]);
    extractWin<11, 0, false>(min(lane + 128, 164), M, MH, pcS[2], ocS[2], ixS[2]);
    extractWin<15, 0, false>(lane,                 M, MV, pcS[3], ocS[3], ixS[3]);
    extractWin<15, 0, false>(lane + 64,            M, MV, pcS[4], ocS[4], ixS[4]);
    extractWin<15, 0, false>(min(lane + 128, 164), M, MV, pcS[5], ocS[5], ixS[5]);
    extractWin<11, 0, true >(lane,                 M, MD, pcS[6], ocS[6], ixS[6]);
    extractWin<11, 0, true >(min(lane + 64, 120),  M, MD, pcS[7], ocS[7], ixS[7]);
    extractWin<11, 4, false>(lane,                 M, MA, pcS[8], ocS[8], ixS[8]);
    extractWin<11, 4, false>(min(lane + 64, 120),  M, MA, pcS[9], ocS[9], ixS[9]);

    float baseLocal = 0.f;
    scoreWin<1> (true, pcS[0], ocS[0], ixS[0], bD, bW, baseLocal);
    scoreWin<1> (true, pcS[1], ocS[1], ixS[1], bD, bW, baseLocal);
    scoreWin<1> (a2,   pcS[2], ocS[2], ixS[2], bD, bW, baseLocal);
    scoreWin<15>(true, pcS[3], ocS[3], ixS[3], bD, bW, baseLocal);
    scoreWin<15>(true, pcS[4], ocS[4], ixS[4], bD, bW, baseLocal);
    scoreWin<15>(a2,   pcS[5], ocS[5], ixS[5], bD, bW, baseLocal);
    scoreWin<16>(true, pcS[6], ocS[6], ixS[6], bD, bW, baseLocal);
    scoreWin<16>(a7,   pcS[7], ocS[7], ixS[7], bD, bW, baseLocal);
    scoreWin<14>(true, pcS[8], ocS[8], ixS[8], bD, bW, baseLocal);
    scoreWin<14>(a7,   pcS[9], ocS[9], ixS[9], bD, bW, baseLocal);

    __threadfence_block();  // drain same-wave scatter before gather

    const float base = wredSum(baseLocal);

    const u64 C0 = M.P0 | M.O0, C1 = M.P1 | M.O1, C2 = M.P2 | M.O2, C3 = M.P3 | M.O3;

    float* __restrict__ pl = ws + (size_t)b * NA;
    #pragma unroll
    for (int j = 0; j < 4; ++j) {
        const int c = lane + 64 * j;
        if (c < NA) {
            const u64 Cj = j == 0 ? C0 : j == 1 ? C1 : j == 2 ? C2 : C3;
            const bool isEmpty = ((Cj >> lane) & 1ULL) == 0ULL;
            float lg = -1000000.f;
            if (isEmpty) lg = (bW[c] > 0.f) ? 100000.f : base + bD[c];
            pl[c] = lg;
        }
    }
    if (lane == 0) ws[(size_t)B * NA + b] = base;
}

// ---- k2: streaming epilogue (no LDS): stats + noise + softmax + value ----
__global__ __launch_bounds__(256, 4) void sm_kernel(
    const float* __restrict__ ws, const float* __restrict__ pnoise,
    const float* __restrict__ vnoise, float* __restrict__ out, int B)
{
    const int wid  = threadIdx.x >> 6;
    const int lane = threadIdx.x & 63;
    const int b    = blockIdx.x * 4 + wid;
    if (b >= B) return;

    const float* __restrict__ pl = ws + (size_t)b * NA;
    const float* __restrict__ pn = pnoise + (size_t)b * NA;

    float lg[4], pnv[4];
    #pragma unroll
    for (int j = 0; j < 4; ++j) {
        const int c = lane + 64 * j;
        lg[j]  = (c < NA) ? pl[c] : -1000000.f;
        pnv[j] = (c < NA) ? pn[c] : 0.f;
    }
    const float vnb  = vnoise[b];
    const float base = ws[(size_t)B * NA + b];

    float nLoc = 0.f, sLoc = 0.f;
    #pragma unroll
    for (int j = 0; j < 4; ++j) {
        const int c = lane + 64 * j;
        if (c < NA && lg[j] > -100000.f) { nLoc += 1.f; sLoc += lg[j]; }
    }
    #pragma unroll
    for (int off = 32; off; off >>= 1) {
        nLoc += __shfl_xor(nLoc, off, 64);
        sLoc += __shfl_xor(sLoc, off, 64);
    }
    const float nsafe = fmaxf(nLoc, 1.f);
    const float mean  = sLoc / nsafe;

    float vLoc = 0.f;
    #pragma unroll
    for (int j = 0; j < 4; ++j) {
        const int c = lane + 64 * j;
        if (c < NA && lg[j] > -100000.f) {
            const float dv = lg[j] - mean;
            vLoc += dv * dv;
        }
    }
    const float var  = wredSum(vLoc) / nsafe;
    const float std_ = fmaxf(1.f, sqrtf(var));
    const float nsc  = 2.0f * std_;
    const bool  anyValid = nLoc > 0.f;

    #pragma unroll
    for (int j = 0; j < 4; ++j) {
        const int c = lane + 64 * j;
        if (c < NA && lg[j] > -100000.f && anyValid)
            lg[j] += pnv[j] * nsc;
    }

    float xs[4];
    float mLoc = -INFINITY;
    #pragma unroll
    for (int j = 0; j < 4; ++j) {
        const int c = lane + 64 * j;
        xs[j] = lg[j] * 0.03f;
        if (c < NA) mLoc = fmaxf(mLoc, xs[j]);
    }
    const float m = wredMax(mLoc);

    float ev[4];
    float eLoc = 0.f;
    #pragma unroll
    for (int j = 0; j < 4; ++j) {
        const int c = lane + 64 * j;
        ev[j] = (c < NA) ? __expf(xs[j] - m) : 0.f;
        eLoc += ev[j];
    }
    const float inv = 1.f / wredSum(eLoc);

    float* __restrict__ po = out + (size_t)b * NA;
    #pragma unroll
    for (int j = 0; j < 4; ++j) {
        const int c = lane + 64 * j;
        if (c < NA) po[c] = ev[j] * inv;
    }

    if (lane == 0) {
        float v = tanhf((base + vnb * 200.0f) / 3000.0f);
        v = fminf(0.95f, fmaxf(-0.95f, v));
        out[(size_t)B * NA + b] = v;
    }
}

extern "C" void kernel_launch(void* const* d_in, const int* in_sizes, int n_in,
                              void* d_out, int out_size, void* d_ws, size_t ws_size,
                              hipStream_t stream) {
    const int*   boards = (const int*)d_in[0];
    const int*   cur    = (const int*)d_in[1];
    const float* pn     = (const float*)d_in[2];
    const float* vn     = (const float*)d_in[3];
    float*       outp   = (float*)d_out;
    float*       wsf    = (float*)d_ws;
    const int B = in_sizes[1];  // current_player has B elements

    const int grid = (B + 3) / 4;  // 4 boards per block (one per wave)
    win_kernel<<<grid, 256, 0, stream>>>(boards, cur, wsf, B);
    sm_kernel <<<grid, 256, 0, stream>>>(wsf, pn, vn, outp, B);
}

// Round 13
// 95.567 us; speedup vs baseline: 1.2237x; 1.2237x over previous
//
#include <hip/hip_runtime.h>
#include <math.h>

#define BSZ 15
#define NA  225
typedef unsigned long long u64;

// weight chain (cndmask, no indexed array)
__device__ __forceinline__ float wtab(int n) {  // n>=1; n>=5 -> 1e5
    return n == 1 ? 5.f : n == 2 ? 50.f : n == 3 ? 500.f : n == 4 ? 5000.f : 100000.f;
}
__device__ __forceinline__ float wredSum(float v) {
    #pragma unroll
    for (int off = 32; off; off >>= 1) v += __shfl_xor(v, off, 64);
    return v;
}
__device__ __forceinline__ float wredMax(float v) {
    #pragma unroll
    for (int off = 32; off; off >>= 1) v = fmaxf(v, __shfl_xor(v, off, 64));
    return v;
}

struct Masks { u64 P0, P1, P2, P3, O0, O1, O2, O3; };

// extraction: pc/oc from wave-uniform bitboards, pure VALU/SALU.
template<int DIV, int CEXTRA, bool HAS64>
__device__ __forceinline__ void extractWin(int u, const Masks& M, u64 wmask,
                                           int& pc, int& oc)
{
    const int r = u / DIV;              // compile-time divisor -> magic mul
    const int c = u % DIV + CEXTRA;
    const int idx = r * BSZ + c;
    const int q = idx >> 6, sh = idx & 63;
    const u64 Plo = (q & 2) ? ((q & 1) ? M.P3 : M.P2) : ((q & 1) ? M.P1 : M.P0);
    const u64 Phi = (q & 2) ? ((q & 1) ? 0ULL : M.P3) : ((q & 1) ? M.P2 : M.P1);
    const u64 Olo = (q & 2) ? ((q & 1) ? M.O3 : M.O2) : ((q & 1) ? M.O1 : M.O0);
    const u64 Ohi = (q & 2) ? ((q & 1) ? 0ULL : M.O3) : ((q & 1) ? M.O2 : M.O1);
    const u64 xP = (Plo >> sh) | ((Phi << (63 - sh)) << 1);  // sh==0 safe
    const u64 xO = (Olo >> sh) | ((Ohi << (63 - sh)) << 1);
    pc = __popcll(xP & wmask);
    oc = __popcll(xO & wmask);
    if (HAS64) {  // step-16 window spans 65 bits: cell4 = bit sh of hi chunk
        pc += (int)((Phi >> sh) & 1ULL);
        oc += (int)((Ohi >> sh) & 1ULL);
    }
}

// branchless s0 and d for a window. Reachable d values:
//   oc==0: {5,45,450,4500,95000} (pc=0..4);  pc==0,oc>0: {5,50,500,5000,100000};
//   mixed: 0.  So d==95000 uniquely marks pc==4 && oc==0 (the win windows).
__device__ __forceinline__ void scoreD(int pc, int oc, float& s0, float& d) {
    const bool z_oc = (oc == 0), z_pc = (pc == 0);
    s0 = z_oc ? (z_pc ? 0.f : wtab(pc)) : (z_pc ? -wtab(oc) : 0.f);
    d  = (z_oc ? wtab(pc + 1) : 0.f) - s0;
}

// One wave = one board, 4 boards/block, no __syncthreads, no LDS atomics.
// Scatter inverted to a gather through a per-window d-value table.
__global__ __launch_bounds__(256, 4) void heur_kernel(
    const int* __restrict__ boards, const int* __restrict__ cur,
    const float* __restrict__ pnoise, const float* __restrict__ vnoise,
    float* __restrict__ out, int B)
{
    const int wid  = threadIdx.x >> 6;
    const int lane = threadIdx.x & 63;
    const int b    = blockIdx.x * 4 + wid;

    // d-value table, window-indexed: [0,165) H, [165,330) V, [330,451) D, [451,572) A
    __shared__ float sDW[4][572];

    if (b >= B) return;  // whole wave exits together; no barriers

    float* __restrict__ dw = sDW[wid];

    const int player = cur[b];
    const int opp    = 3 - player;
    const int* __restrict__ gb = boards + (size_t)b * NA;

    // lane holds cells lane+64j (chunk j, bit position = lane)
    const int v0 = gb[lane];
    const int v1 = gb[lane + 64];
    const int v2 = gb[lane + 128];
    const int v3 = (lane + 192 < NA) ? gb[lane + 192] : -1;

    // noise loads issued early; latency hides under the VALU window pass
    const float* __restrict__ pn = pnoise + (size_t)b * NA;
    float pnv[4];
    pnv[0] = pn[lane];
    pnv[1] = pn[lane + 64];
    pnv[2] = pn[lane + 128];
    pnv[3] = (lane + 192 < NA) ? pn[lane + 192] : 0.f;
    const float vnb = vnoise[b];

    Masks M;
    M.P0 = __ballot(v0 == player); M.O0 = __ballot(v0 == opp);
    M.P1 = __ballot(v1 == player); M.O1 = __ballot(v1 == opp);
    M.P2 = __ballot(v2 == player); M.O2 = __ballot(v2 == opp);
    M.P3 = __ballot(v3 == player); M.O3 = __ballot(v3 == opp);

    // ---- phase A: extract all 10 window slots (independent VALU chains) ----
    const u64 MH = 0x1FULL;
    const u64 MV = 0x1000200040008001ULL;   // bits 0,15,30,45,60
    const u64 MD = 0x0001000100010001ULL;   // bits 0,16,32,48 (+bit64)
    const u64 MA = 0x0100040010004001ULL;   // bits 0,14,28,42,56

    int pcS[10], ocS[10];
    const bool a2 = lane < 37, a7 = lane < 57;
    extractWin<11, 0, false>(lane,                 M, MH, pcS[0], ocS[0]);
    extractWin<11, 0, false>(lane + 64,            M, MH, pcS[1], ocS[1]);
    extractWin<11, 0, false>(min(lane + 128, 164), M, MH, pcS[2], ocS[2]);
    extractWin<15, 0, false>(lane,                 M, MV, pcS[3], ocS[3]);
    extractWin<15, 0, false>(lane + 64,            M, MV, pcS[4], ocS[4]);
    extractWin<15, 0, false>(min(lane + 128, 164), M, MV, pcS[5], ocS[5]);
    extractWin<11, 0, true >(lane,                 M, MD, pcS[6], ocS[6]);
    extractWin<11, 0, true >(min(lane + 64, 120),  M, MD, pcS[7], ocS[7]);
    extractWin<11, 4, false>(lane,                 M, MA, pcS[8], ocS[8]);
    extractWin<11, 4, false>(min(lane + 64, 120),  M, MA, pcS[9], ocS[9]);

    // ---- phase B: score + plain (single-writer, conflict-free) d-table writes ----
    float baseLocal = 0.f;
    float s0v[10], dv[10];
    #pragma unroll
    for (int t = 0; t < 10; ++t) scoreD(pcS[t], ocS[t], s0v[t], dv[t]);
    const bool act[10] = {true, true, a2, true, true, a2, true, a7, true, a7};
    #pragma unroll
    for (int t = 0; t < 10; ++t) if (act[t]) baseLocal += s0v[t];

    dw[lane]             = dv[0];
    dw[lane + 64]        = dv[1];
    if (a2) dw[lane + 128] = dv[2];
    dw[165 + lane]       = dv[3];
    dw[165 + lane + 64]  = dv[4];
    if (a2) dw[165 + lane + 128] = dv[5];
    dw[330 + lane]       = dv[6];
    if (a7) dw[330 + lane + 64]  = dv[7];
    dw[451 + lane]       = dv[8];
    if (a7) dw[451 + lane + 64]  = dv[9];

    __threadfence_block();  // same-wave DS ordering before gather

    const float base = wredSum(baseLocal);

    // ---- phase C: per-cell gather (<=20 independent coalesced LDS reads) ----
    const u64 C0 = M.P0 | M.O0, C1 = M.P1 | M.O1, C2 = M.P2 | M.O2, C3 = M.P3 | M.O3;

    float logitv[4];
    float nLoc = 0.f, sLoc = 0.f;
    #pragma unroll
    for (int j = 0; j < 4; ++j) {
        const int cl = lane + 64 * j;
        float lg = -1000000.f;
        if (cl < NA) {
            const int r = cl / BSZ, c = cl % BSZ;   // const divisor -> magic mul
            float acc = 0.f;
            bool  wf  = false;
            #pragma unroll
            for (int k = 0; k < 5; ++k) {
                const int wr = r - k;               // start row for V,D,A taps
                const int wcH = c - k;              // start col for H,D
                const int wcA = c + k - 4;          // A-table col (c+k-4 = wc-4)
                const bool vR = (unsigned)wr  < 11u;
                const bool vH = (unsigned)wcH < 11u;
                const bool vA = (unsigned)wcA < 11u;
                if (vH)        { const float v = dw[r * 11 + wcH];          acc += v; wf |= (v == 95000.f); }
                if (vR)        { const float v = dw[165 + wr * 15 + c];     acc += v; wf |= (v == 95000.f); }
                if (vR && vH)  { const float v = dw[330 + wr * 11 + wcH];   acc += v; wf |= (v == 95000.f); }
                if (vR && vA)  { const float v = dw[451 + wr * 11 + wcA];   acc += v; wf |= (v == 95000.f); }
            }
            const u64 Cj = j == 0 ? C0 : j == 1 ? C1 : j == 2 ? C2 : C3;
            const bool isEmpty = ((Cj >> lane) & 1ULL) == 0ULL;
            if (isEmpty) lg = wf ? 100000.f : base + acc;
        }
        logitv[j] = lg;
        if (cl < NA && lg > -100000.f) { nLoc += 1.f; sLoc += lg; }
    }

    // ---- stats + noise + softmax + value ----
    #pragma unroll
    for (int off = 32; off; off >>= 1) {
        nLoc += __shfl_xor(nLoc, off, 64);
        sLoc += __shfl_xor(sLoc, off, 64);
    }
    const float nsafe = fmaxf(nLoc, 1.f);
    const float mean  = sLoc / nsafe;

    float vLoc = 0.f;
    #pragma unroll
    for (int j = 0; j < 4; ++j) {
        const int cl = lane + 64 * j;
        if (cl < NA && logitv[j] > -100000.f) {
            const float dvv = logitv[j] - mean;
            vLoc += dvv * dvv;
        }
    }
    const float var  = wredSum(vLoc) / nsafe;
    const float std_ = fmaxf(1.f, sqrtf(var));
    const float nsc  = 2.0f * std_;
    const bool  anyValid = nLoc > 0.f;

    #pragma unroll
    for (int j = 0; j < 4; ++j) {
        const int cl = lane + 64 * j;
        if (cl < NA && logitv[j] > -100000.f && anyValid)
            logitv[j] += pnv[j] * nsc;
    }

    float xs[4];
    float mLoc = -INFINITY;
    #pragma unroll
    for (int j = 0; j < 4; ++j) {
        const int cl = lane + 64 * j;
        xs[j] = logitv[j] * 0.03f;
        if (cl < NA) mLoc = fmaxf(mLoc, xs[j]);
    }
    const float m = wredMax(mLoc);

    float ev[4];
    float eLoc = 0.f;
    #pragma unroll
    for (int j = 0; j < 4; ++j) {
        const int cl = lane + 64 * j;
        ev[j] = (cl < NA) ? __expf(xs[j] - m) : 0.f;
        eLoc += ev[j];
    }
    const float inv = 1.f / wredSum(eLoc);

    float* __restrict__ po = out + (size_t)b * NA;
    #pragma unroll
    for (int j = 0; j < 4; ++j) {
        const int cl = lane + 64 * j;
        if (cl < NA) po[cl] = ev[j] * inv;
    }

    if (lane == 0) {
        float v = tanhf((base + vnb * 200.0f) / 3000.0f);
        v = fminf(0.95f, fmaxf(-0.95f, v));
        out[(size_t)B * NA + b] = v;
    }
}

extern "C" void kernel_launch(void* const* d_in, const int* in_sizes, int n_in,
                              void* d_out, int out_size, void* d_ws, size_t ws_size,
                              hipStream_t stream) {
    const int*   boards = (const int*)d_in[0];
    const int*   cur    = (const int*)d_in[1];
    const float* pn     = (const float*)d_in[2];
    const float* vn     = (const float*)d_in[3];
    float*       outp   = (float*)d_out;
    const int B = in_sizes[1];  // current_player has B elements

    const int grid = (B + 3) / 4;  // 4 boards per block (one per wave)
    heur_kernel<<<grid, 256, 0, stream>>>(boards, cur, pn, vn, outp, B);
}